// Round 6
// baseline (235.849 us; speedup 1.0000x reference)
//
#include <hip/hip_runtime.h>
#include <hip/hip_fp16.h>

#define BLANKC 59
#define NEGF (-1e30f)

typedef _Float16 half8 __attribute__((ext_vector_type(8)));

// ---------------- Phase 1: log-softmax + gather, TRANSPOSED output ----------
// em layout: [B][48 slots][T] halves. slot l (0..44) = logp[lab[b][l]],
// slot 45 = logp[BLANK]. One block per (b, 64-t tile).
#define TTILE 64
__global__ __launch_bounds__(256)
void ctc_emit(const int* __restrict__ labels, const float* __restrict__ logits,
              __half* __restrict__ em, int T, int V, int L) {
    const int tiles_per_b = 384 / TTILE;                 // T = 384
    const int b  = blockIdx.x / tiles_per_b;
    const int t0 = (blockIdx.x % tiles_per_b) * TTILE;
    const int tid = threadIdx.x;

    __shared__ float ftile[TTILE][61];                   // stride 61: conflict-free
    __shared__ __half otile[48][72];                     // stride 72 halves (16B-aligned rows)

    // --- load 64 rows x 60 logits, coalesced dwords ---
    const float* src = logits + ((long)b * T + t0) * V;  // 3840 contiguous floats
    #pragma unroll
    for (int it = 0; it < 15; ++it) {
        const int idx = it * 256 + tid;                  // 0..3839
        const int r = idx / 60, c = idx - r * 60;
        ftile[r][c] = src[idx];
    }
    __syncthreads();

    // --- per-t LSE + gather (threads 0..63, one t each) ---
    if (tid < TTILE) {
        const int t = tid;
        float s = 0.f;
        #pragma unroll
        for (int k = 0; k < 60; ++k) s += __expf(ftile[t][k]);
        const float lse = __logf(s);
        const int* lab = labels + (long)b * L;           // wave-uniform reads
        #pragma unroll
        for (int l = 0; l < 45; ++l) {
            const int v = lab[l];
            otile[l][t] = __float2half(ftile[t][v] - lse);
        }
        otile[45][t] = __float2half(ftile[t][BLANKC] - lse);
    }
    __syncthreads();

    // --- cooperative transposed store: 46 slots x 64 halves (128 B each) ---
    for (int i = tid; i < 46 * 8; i += 256) {
        const int slot = i >> 3, seg = i & 7;
        const float4 v = *(const float4*)&otile[slot][seg * 8];
        float4* dst = (float4*)(em + ((long)b * 48 + slot) * T + t0 + seg * 8);
        *dst = v;
    }
}

// ---------------- Phase 2: alpha recurrence, one wave per batch element -----
// Lane l owns s0 = 2l (blank) and s1 = 2l+1 (label l). One shfl_up per step.
// Chunks live in VGPRs via ext_vector_type (NO address-taking -> no scratch).
__global__ __launch_bounds__(64)
void ctc_alpha(const int* __restrict__ labels, const __half* __restrict__ em,
               float* __restrict__ out, int T, int L, float inv_b) {
    const int b    = blockIdx.x;
    const int lane = threadIdx.x;

    const int* lab = labels + (long)b * L;
    const int labL = (lane < L) ? lab[lane] : BLANKC;
    const int labP = (lane >= 1 && lane < L) ? lab[lane - 1] : BLANKC;
    const bool skip = (lane >= 1) && (lane < L) && (labL != BLANKC) && (labL != labP);

    unsigned long long mk = __ballot((lane < L) && (labL != BLANKC));
    const int len = __popcll(mk);

    const int li = (lane < 46) ? lane : 45;
    const half8* rowL = (const half8*)(em + ((long)b * 48 + li) * T);
    const half8* rowB = (const half8*)(em + ((long)b * 48 + 45) * T);

    // 2-deep chunk prefetch, all held in VGPRs
    half8 curL = rowL[0], curB = rowB[0];
    half8 n1L  = rowL[1], n1B  = rowB[1];
    half8 n2L  = rowL[2], n2B  = rowB[2];

    float a0 = (lane == 0) ? (float)curB[0] : NEGF;  // s=0: blank @ t=0
    float a1 = (lane == 0) ? (float)curL[0] : NEGF;  // s=1: first label @ t=0
    float m01 = fmaxf(a0, a1);                       // hoisted off next step's chain

    auto step = [&](float eL, float eB) {
        float p = __shfl_up(a1, 1, 64);              // alpha_old[2l-1]
        p = (lane >= 1) ? p : NEGF;
        const float ps = skip ? p : NEGF;
        const float m0 = fmaxf(a0, p);
        const float na0 = m0 + __logf(__expf(a0 - m0) + __expf(p - m0)) + eB;
        const float m1 = fmaxf(m01, ps);
        const float na1 = m1 + __logf(__expf(a1 - m1) + __expf(a0 - m1) + __expf(ps - m1)) + eL;
        a0 = na0; a1 = na1;
        m01 = fmaxf(a0, a1);
    };

    // peeled chunk 0: t = 1..7
    #pragma unroll
    for (int i = 1; i < 8; ++i) step((float)curL[i], (float)curB[i]);

    const int NC = T / 8;                            // 48 chunks
    for (int c = 1; c < NC; ++c) {
        curL = n1L; curB = n1B;
        n1L = n2L;  n1B = n2B;
        if (c + 2 < NC) { n2L = rowL[c + 2]; n2B = rowB[c + 2]; }
        #pragma unroll
        for (int i = 0; i < 8; ++i) step((float)curL[i], (float)curB[i]);
    }

    // epilogue: end = 2*len -> lane len's a0; end-1 -> lane (len-1)'s a1
    const float ab2 = __shfl(a0, len, 64);
    float al2 = __shfl(a1, (len > 0) ? len - 1 : 0, 64);
    al2 = (len > 0) ? al2 : NEGF;
    if (lane == 0) {
        const float mm  = fmaxf(ab2, al2);
        const float nll = -(mm + __logf(__expf(ab2 - mm) + __expf(al2 - mm)));
        atomicAdd(out, nll * inv_b);
    }
}

extern "C" void kernel_launch(void* const* d_in, const int* in_sizes, int n_in,
                              void* d_out, int out_size, void* d_ws, size_t ws_size,
                              hipStream_t stream) {
    const int* labels   = (const int*)d_in[0];
    const float* logits = (const float*)d_in[1];
    float* out          = (float*)d_out;
    __half* em          = (__half*)d_ws;        // B*48*T*2 = 36 MB

    const int L = 45, V = 60;
    const int B = in_sizes[0] / L;
    const int T = in_sizes[1] / (B * V);

    hipMemsetAsync(out, 0, (size_t)out_size * sizeof(float), stream);
    ctc_emit<<<B * (T / TTILE), 256, 0, stream>>>(labels, logits, em, T, V, L);
    ctc_alpha<<<B, 64, 0, stream>>>(labels, em, out, T, L, 1.0f / (float)B);
}